// Round 6
// baseline (156.975 us; speedup 1.0000x reference)
//
#include <hip/hip_runtime.h>

typedef unsigned short u16;
typedef __attribute__((ext_vector_type(4))) unsigned short u16x4;
typedef __attribute__((ext_vector_type(8))) short bf16x8;
typedef __attribute__((ext_vector_type(4))) float f32x4;

#define B_ 4
#define T_ 1024
#define NH 12
#define HS 64
#define CDIM 768
#define QKVW 2304   // 3*CDIM
#define NC 16
#define CS 64
#define LAM 0.99f
#define BP  (0.01f/0.99f)
#define MROWS 4096
#define LSTR 72     // bf16 LDS row stride: 144B, 16B-aligned, 2-way banks (free)

// ws layout (float offsets). qkv bf16 at ws[0] (span 4718592 floats).
// [4718592, 9437184) is permanently free -> wpT lives there.
#define OFF_WPT 4718592
#define OFF_W  9437184
#define OFF_U  (OFF_W  + 768*4096)   // bf16 permuted U (u16, half-used)
#define OFF_C  (OFF_U  + 768*4096)   // bf16 permuted C; later bf16 ob (aliased)
#define OFF_R0 (OFF_C  + 768*4096)   // bf16 swizzled R0^T (u16)
#define OFF_XB (OFF_W)                       // bf16 x
#define OFF_WAT (OFF_W + 1572864)            // bf16 w_attn^T
// d_out doubles as scratch: wbg (bf16 W, swizzled) + ktg (bf16 K^T, swizzled)

__device__ __forceinline__ u16 f2bf(float f) {
    union { float f; unsigned u; } a; a.f = f;
    const unsigned r = a.u + 0x7FFF + ((a.u >> 16) & 1);
    return (u16)(r >> 16);
}
__device__ __forceinline__ float bf2f(u16 h) {
    union { unsigned u; float f; } a; a.u = ((unsigned)h) << 16; return a.f;
}
__device__ __forceinline__ u16x4 f2bf4(const f32x4 v) {
    u16x4 u; u.x = f2bf(v[0]); u.y = f2bf(v[1]); u.z = f2bf(v[2]); u.w = f2bf(v[3]);
    return u;
}
// swizzled stride-64 LDS index (matches the wbg/ktg global layout and the
// ks = kq ^ ((ln&7)*8) read path in mm_stripN's SWZ=true mode)
__device__ __forceinline__ int swz(int row, int col) {
    return row * 64 + (((col >> 3) ^ (row & 7)) << 3) + (col & 7);
}

// ---------------- merged cast kernel ------------------------------------
// blocks [0,3072): x -> bf16 xb (straight)
// blocks [3072,3504): w_attn [768][2304] -> waT [2304][768] bf16
// blocks [3504,3648): w_proj [768][768]  -> wpT [768][768]  bf16
__device__ __forceinline__ void tcast_body(const float* __restrict__ src,
                                           u16* __restrict__ dst,
                                           int Cn, int Rr, int bx, int by) {
    const int ln = threadIdx.x & 63, kg = threadIdx.x >> 6;
    const int n = bx * 64 + ln;
    const int kb = by * 64 + kg * 16;
    u16 tmp[16];
#pragma unroll
    for (int j = 0; j < 16; ++j)
        tmp[j] = f2bf(src[(size_t)(kb + j) * Cn + n]);
#pragma unroll
    for (int j4 = 0; j4 < 4; ++j4) {
        u16x4 u; u.x = tmp[j4*4]; u.y = tmp[j4*4+1]; u.z = tmp[j4*4+2]; u.w = tmp[j4*4+3];
        *(u16x4*)&dst[(size_t)n * Rr + kb + j4*4] = u;
    }
}

__global__ __launch_bounds__(256)
void cast_all_kernel(const float* __restrict__ x, const float* __restrict__ wa,
                     const float* __restrict__ wp, u16* __restrict__ xb,
                     u16* __restrict__ waT, u16* __restrict__ wpT) {
    const int bid = blockIdx.x;
    if (bid < 3072) {
        const size_t i = ((size_t)bid * 256 + threadIdx.x) * 4;
        const float4 v = *(const float4*)(x + i);
        u16x4 u;
        u.x = f2bf(v.x); u.y = f2bf(v.y); u.z = f2bf(v.z); u.w = f2bf(v.w);
        *(u16x4*)(xb + i) = u;
    } else if (bid < 3504) {
        const int idx = bid - 3072;
        tcast_body(wa, waT, QKVW, CDIM, idx % 36, idx / 36);
    } else {
        const int idx = bid - 3504;
        tcast_body(wp, wpT, CDIM, CDIM, idx % 12, idx / 12);
    }
}

// ---------------- MFMA GEMM: C[M,N] = A[M,K] @ Bt[N,K]^T ----------------
// Tile: (32*MI_T) x 128. 1D grid with XCD-aware RECT swizzle: xcd = bid&7,
// slot = bid>>3; each XCD owns an RW x RH rectangle of output tiles so its
// resident blocks' operand panels fit the 4 MB per-XCD L2 (gemm1: 9x8 rect
// -> 3.3 MB working set; default round-robin spreads ~10 MB over each L2).
// Pure index remap -> bitwise identical output. Requires grid == 8*RW*RH.
// NORM: per-64-col-group standardization epilogue, bf16 out. Else fp32 (+R).
__device__ __forceinline__ void gll16(const u16* g, u16* lds) {
    __builtin_amdgcn_global_load_lds(
        (const __attribute__((address_space(1))) unsigned*)g,
        (__attribute__((address_space(3))) unsigned*)lds, 16, 0, 0);
}

template<bool ADD_RES, bool NORM, int MI_T, int MINW, int XC, int RW, int RH>
__global__ __launch_bounds__(256, MINW)
void gemm_mfma(const u16* __restrict__ A, const u16* __restrict__ Bt,
               const float* __restrict__ R, void* __restrict__ Cout,
               int N, int K) {
    __shared__ u16 As[32 * MI_T * 64];
    __shared__ u16 Bs[128 * 64];
    const int tid  = threadIdx.x;
    const int wave = tid >> 6, lane = tid & 63;
    const int wm = wave >> 1, wn = wave & 1;
    const int ln = lane & 15, quad = lane >> 4;

    const int bid = blockIdx.x;
    const int xcd = bid & 7, slot = bid >> 3;
    const int tx = (xcd % XC) * RW + slot % RW;
    const int ty = (xcd / XC) * RH + slot / RW;
    const int m0 = ty * (32 * MI_T), n0 = tx * 128;

    const int rl = lane >> 3;
    const int kx = ((lane & 7) ^ rl) * 8;
    const u16* Ag = A + (size_t)(m0 + wave * (8 * MI_T) + rl) * K + kx;
    const u16* Bg = Bt + (size_t)(n0 + wave * 32 + rl) * K + kx;
    u16* AsW = &As[(wave * (8 * MI_T)) * 64];
    u16* BsW = &Bs[(wave * 32) * 64];

    f32x4 acc[MI_T][4] = {};

    for (int k0 = 0; k0 < K; k0 += 64) {
        __syncthreads();
#pragma unroll
        for (int c8 = 0; c8 < MI_T; ++c8)
            gll16(Ag + (size_t)(c8 * 8) * K + k0, AsW + c8 * 8 * 64);
#pragma unroll
        for (int c8 = 0; c8 < 4; ++c8)
            gll16(Bg + (size_t)(c8 * 8) * K + k0, BsW + c8 * 8 * 64);
        __syncthreads();
#pragma unroll
        for (int k32 = 0; k32 < 64; k32 += 32) {
            const int ko = (k32 + quad * 8) ^ ((ln & 7) * 8);
            bf16x8 af[MI_T], bfr[4];
#pragma unroll
            for (int mi = 0; mi < MI_T; ++mi)
                af[mi] = *(const bf16x8*)&As[(wm * (16 * MI_T) + mi * 16 + ln) * 64 + ko];
#pragma unroll
            for (int ni = 0; ni < 4; ++ni)
                bfr[ni] = *(const bf16x8*)&Bs[(wn * 64 + ni * 16 + ln) * 64 + ko];
#pragma unroll
            for (int mi = 0; mi < MI_T; ++mi)
#pragma unroll
                for (int ni = 0; ni < 4; ++ni)
                    acc[mi][ni] = __builtin_amdgcn_mfma_f32_16x16x32_bf16(
                        af[mi], bfr[ni], acc[mi][ni], 0, 0, 0);
        }
    }

#pragma unroll
    for (int mi = 0; mi < MI_T; ++mi) {
        const int rb = m0 + wm * (16 * MI_T) + mi * 16 + quad * 4;
#pragma unroll
        for (int r = 0; r < 4; ++r) {
            if (NORM) {
                const float a0 = acc[mi][0][r], a1 = acc[mi][1][r];
                const float a2 = acc[mi][2][r], a3 = acc[mi][3][r];
                float s1 = a0 + a1 + a2 + a3;
                float s2 = a0*a0 + a1*a1 + a2*a2 + a3*a3;
#pragma unroll
                for (int m = 1; m < 16; m <<= 1) {
                    s1 += __shfl_xor(s1, m, 64);
                    s2 += __shfl_xor(s2, m, 64);
                }
                const float mu = s1 * (1.0f / 64.0f);
                const float rs = rsqrtf((s2 - 64.0f * mu * mu) * (1.0f / 63.0f));
                u16* op = (u16*)Cout + (size_t)(rb + r) * N + n0 + wn * 64 + ln;
                op[0]  = f2bf((a0 - mu) * rs);
                op[16] = f2bf((a1 - mu) * rs);
                op[32] = f2bf((a2 - mu) * rs);
                op[48] = f2bf((a3 - mu) * rs);
            } else {
#pragma unroll
                for (int ni = 0; ni < 4; ++ni) {
                    const int col = n0 + wn * 64 + ni * 16 + ln;
                    float v = acc[mi][ni][r];
                    if (ADD_RES) v += R[(size_t)(rb + r) * N + col];
                    ((float*)Cout)[(size_t)(rb + r) * N + col] = v;
                }
            }
        }
    }
}

// ---------------- MFMA strip microkernels -------------------------------
template<bool ASWZ, bool BSWZ, int NT>
__device__ __forceinline__ void mm_stripN(const u16* A, const u16* Bq,
                                          int wr, int ln, int quad, f32x4 (&acc)[NT]) {
#pragma unroll
    for (int k0 = 0; k0 < 64; k0 += 32) {
        const int kq = k0 + quad * 8;
        const int ks = kq ^ ((ln & 7) * 8);
        const bf16x8 a = ASWZ ? *(const bf16x8*)&A[(wr + ln) * 64 + ks]
                              : *(const bf16x8*)&A[(wr + ln) * LSTR + kq];
#pragma unroll
        for (int nt = 0; nt < NT; ++nt) {
            const bf16x8 b = BSWZ ? *(const bf16x8*)&Bq[(nt * 16 + ln) * 64 + ks]
                                  : *(const bf16x8*)&Bq[(nt * 16 + ln) * LSTR + kq];
            acc[nt] = __builtin_amdgcn_mfma_f32_16x16x32_bf16(a, b, acc[nt], 0, 0, 0);
        }
    }
}

template<bool ASWZ, bool BSWZ>
__device__ __forceinline__ void mm_strip2(const u16* A, const u16* Bq,
                                          int wr, int ln, int quad, f32x4 (&acc)[4]) {
    mm_stripN<ASWZ, BSWZ, 4>(A, Bq, wr, ln, quad, acc);
}

// ---------------- Kernel A (MFMA): per-(bh,chunk) W, U, C ---------------
// All 5 LDS buffers in swizzled stride-64 layout: 5 x 8192 B = 40960 B
// -> 4 blocks/CU. All strip reads have row==ln (mod 8), so the SWZ=true
// read path applies throughout. Bitwise identical to LSTR version.
__global__ __launch_bounds__(256, 4)
void chunkA(const u16* __restrict__ qkv, float* __restrict__ ws,
            u16* __restrict__ wbg, u16* __restrict__ ktg) {
    __shared__ u16 Kb[4096], Vb[4096], KT[4096], VT[4096], NT[4096];
    u16* const Yb = Kb;
    u16* const Np = Vb;
    u16* const UT = NT;
    u16* const HbT = VT;   // VT dead after early c1 strip

    const int cc = blockIdx.x;
    const int bh = cc >> 4, c = cc & 15;
    const int b = bh / NH, h = bh - b * NH;
    const int tid = threadIdx.x;
    const int w = tid >> 6, lane = tid & 63;
    const int ln = lane & 15, quad = lane >> 4;
    const int wr = w * 16;
    const u16* base = qkv + ((size_t)(b * T_ + c * CS)) * QKVW + h * HS;

    {
        const int tr0 = w * 4 + quad;
        const int d0 = ln * 4;
        float vsc = __powf(LAM, -(float)(tr0 + 1));
        const float v16 = __powf(LAM, -16.0f);
#pragma unroll
        for (int p = 0; p < 4; ++p) {
            const int t = p * 16 + tr0;
            const u16x4 k4 = *(const u16x4*)(base + (size_t)t * QKVW + CDIM + d0);
            const u16x4 vu = *(const u16x4*)(base + (size_t)t * QKVW + 2 * CDIM + d0);
            u16x4 v4; v4.x = f2bf(bf2f(vu.x) * vsc); v4.y = f2bf(bf2f(vu.y) * vsc);
            v4.z = f2bf(bf2f(vu.z) * vsc); v4.w = f2bf(bf2f(vu.w) * vsc);
            *(u16x4*)&Kb[swz(t, d0)] = k4;
            *(u16x4*)&Vb[swz(t, d0)] = v4;
            KT[swz(d0 + 0, t)] = k4.x; KT[swz(d0 + 1, t)] = k4.y;
            KT[swz(d0 + 2, t)] = k4.z; KT[swz(d0 + 3, t)] = k4.w;
            VT[swz(d0 + 0, t)] = v4.x; VT[swz(d0 + 1, t)] = v4.y;
            VT[swz(d0 + 2, t)] = v4.z; VT[swz(d0 + 3, t)] = v4.w;
            vsc *= v16;
        }
    }
    __syncthreads();

    f32x4 accG[4] = {}, accH[4] = {}, c1[4] = {};
    mm_strip2<true,true>(Kb, Kb, wr, ln, quad, accG);   // G = K K^T
    mm_strip2<true,true>(Kb, Vb, wr, ln, quad, accH);   // H = K Vt^T
    mm_strip2<true,true>(VT, KT, wr, ln, quad, c1);     // c1 = Vt^T K (hoisted)
    __syncthreads();

#pragma unroll
    for (int nt = 0; nt < 4; ++nt) {
        const int col = nt * 16 + ln;
        u16x4 nvT, hvT;
#pragma unroll
        for (int r = 0; r < 4; ++r) {
            const int row = wr + quad * 4 + r;
            const float g = accG[nt][r];
            const u16 nv = (col < row) ? f2bf(BP * g) : (u16)0;
            Np[swz(row, col)] = nv;
            Yb[swz(row, col)] = (row == col) ? f2bf(1.0f)
                               : ((col < row) ? f2bf(-BP * g) : (u16)0);
            ((u16*)&nvT)[r] = nv;
            ((u16*)&hvT)[r] = (col < row) ? f2bf(accH[nt][r]) : (u16)0;
        }
        *(u16x4*)&NT[swz(col, wr + quad * 4)] = nvT;
        *(u16x4*)&HbT[swz(col, wr + quad * 4)] = hvT;
    }
    __syncthreads();

    for (int j = 0; j < 3; ++j) {
        f32x4 sq[4] = {};
        mm_strip2<true,true>(Np, NT, wr, ln, quad, sq);
        __syncthreads();
#pragma unroll
        for (int nt = 0; nt < 4; ++nt) {
            const int col = nt * 16 + ln;
            u16x4 sv;
#pragma unroll
            for (int r = 0; r < 4; ++r) {
                const u16 v = f2bf(sq[nt][r]);
                Np[swz(wr + quad * 4 + r, col)] = v;
                ((u16*)&sv)[r] = v;
            }
            *(u16x4*)&NT[swz(col, wr + quad * 4)] = sv;
        }
        __syncthreads();
        f32x4 ya[4];
#pragma unroll
        for (int nt = 0; nt < 4; ++nt)
#pragma unroll
            for (int r = 0; r < 4; ++r)
                ya[nt][r] = bf2f(Yb[swz(wr + quad * 4 + r, nt * 16 + ln)]);
        mm_strip2<true,true>(Yb, NT, wr, ln, quad, ya);
#pragma unroll
        for (int nt = 0; nt < 4; ++nt)
#pragma unroll
            for (int r = 0; r < 4; ++r)
                Yb[swz(wr + quad * 4 + r, nt * 16 + ln)] = f2bf(ya[nt][r]);
    }

    u16* Ugp = (u16*)(ws + OFF_U) + (size_t)cc * 4096;
    u16* Cgp = (u16*)(ws + OFF_C) + (size_t)cc * 4096;

    f32x4 wv[4] = {};
    mm_strip2<true,true>(Yb, KT, wr, ln, quad, wv);       // W = Y*K

    f32x4 m1[4] = {};
    mm_strip2<true,true>(Yb, HbT, wr, ln, quad, m1);      // M1 = Y*H_SL
#pragma unroll
    for (int nt = 0; nt < 4; ++nt)
#pragma unroll
        for (int r = 0; r < 4; ++r)
            Np[swz(wr + quad * 4 + r, nt * 16 + ln)] = f2bf(m1[nt][r]);

#pragma unroll
    for (int nt = 0; nt < 4; ++nt)
#pragma unroll
        for (int r = 0; r < 4; ++r)
            Yb[swz(wr + quad * 4 + r, nt * 16 + ln)] = f2bf(wv[nt][r]);

    f32x4 uv[4] = {};
    mm_strip2<true,true>(Np, KT, wr, ln, quad, uv);       // U = M1*K
#pragma unroll
    for (int nt = 0; nt < 4; ++nt)
        *(u16x4*)&Ugp[(size_t)(w * 64 + lane) * 16 + nt * 4] = f2bf4(uv[nt]);
    __syncthreads();
#pragma unroll
    for (int nt = 0; nt < 4; ++nt)
        *(u16x4*)&UT[swz(nt * 16 + ln, wr + quad * 4)] = f2bf4(uv[nt]);
    __syncthreads();

    f32x4 c2[4] = {};
    mm_strip2<true,true>(KT, UT, wr, ln, quad, c2);       // K^T U
#pragma unroll
    for (int nt = 0; nt < 4; ++nt) {
        const f32x4 cv = c1[nt] - BP * c2[nt];
        *(u16x4*)&Cgp[(size_t)(w * 64 + lane) * 16 + nt * 4] = f2bf4(cv);
    }

    // LDS layout == global swizzled layout: straight linear copy
    for (int e = tid; e < 512; e += 256) {
        *(bf16x8*)&wbg[(size_t)cc * 4096 + e * 8] = *(const bf16x8*)&Yb[e * 8];
        *(bf16x8*)&ktg[(size_t)cc * 4096 + e * 8] = *(const bf16x8*)&KT[e * 8];
    }
}

// ---------------- Kernel B (MFMA): sequential 16-chunk sweep ------------
// Column-split: 4 blocks per bh, each owning 16 state columns. Bitwise
// identical to the single-block version (column-separable recurrence).
__global__ __launch_bounds__(256)
void chunkB(float* __restrict__ ws, const u16* __restrict__ wbg,
            const u16* __restrict__ ktg) {
    __shared__ u16 WBs[2][4096], KTs[2][4096];
    __shared__ u16 RTb[16 * LSTR], PTb[16 * LSTR];

    const int bid = blockIdx.x;
    const int bh = bid >> 2, qtr = bid & 3;
    const int cb = qtr * 16;                 // global column base
    const int tid = threadIdx.x;
    const int w = tid >> 6, lane = tid & 63;
    const int ln = lane & 15, quad = lane >> 4;
    const int wr = w * 16;
    const float lam64 = __powf(LAM, 64.0f);
    u16* r0tg = (u16*)(ws + OFF_R0);

    f32x4 R[1] = {};

    for (int e = tid; e < 16 * LSTR; e += 256) RTb[e] = 0;

    const int off = w * 1024;
    {
        const size_t b0 = (size_t)(bh * 16) * 4096;
#pragma unroll
        for (int i = 0; i < 2; ++i) {
            gll16(wbg + b0 + off + i * 512 + lane * 8, &WBs[0][off + i * 512]);
            gll16(ktg + b0 + off + i * 512 + lane * 8, &KTs[0][off + i * 512]);
        }
    }
    __syncthreads();

    for (int c = 0; c < NC; ++c) {
        const int buf = c & 1;
        const size_t cc = (size_t)(bh * 16 + c);

        if (c + 1 < NC) {
            const size_t b1 = (cc + 1) * 4096;
#pragma unroll
            for (int i = 0; i < 2; ++i) {
                gll16(wbg + b1 + off + i * 512 + lane * 8, &WBs[buf ^ 1][off + i * 512]);
                gll16(ktg + b1 + off + i * 512 + lane * 8, &KTs[buf ^ 1][off + i * 512]);
            }
        }

        // C slice for this quarter's 16 cols, loaded early (hides latency)
        const u16* Cg = (const u16*)(ws + OFF_C) + cc * 4096
                        + (size_t)(w * 64 + lane) * 16 + qtr * 4;
        const u16x4 cu = *(const u16x4*)Cg;

        f32x4 p[1] = {};
        mm_stripN<true,false,1>(&WBs[buf][0], RTb, wr, ln, quad, p);  // P[:,cols]
        *(u16x4*)&PTb[ln * LSTR + wr + quad * 4] = f2bf4(p[0]);
        __syncthreads();

        f32x4 kp[1] = {};
        mm_stripN<true,false,1>(&KTs[buf][0], PTb, wr, ln, quad, kp); // K^T P

        u16* r0t = r0tg + cc * 4096;
        const int swzr = (wr + quad * 4) ^ ((ln & 7) * 8);
        const int x = cb + ln;                // global column index
        *(u16x4*)&r0t[x * 64 + swzr] = f2bf4(R[0]);
        f32x4 cv; cv[0] = bf2f(cu.x); cv[1] = bf2f(cu.y);
        cv[2] = bf2f(cu.z); cv[3] = bf2f(cu.w);
        R[0] = lam64 * (R[0] - BP * kp[0] + cv);
        *(u16x4*)&RTb[ln * LSTR + wr + quad * 4] = f2bf4(R[0]);
        __syncthreads();
    }
}

// ---------------- Kernel C (MFMA): outputs per (bh,chunk) ---------------
// LDS: 53248 B -> 3 blocks/CU. RmTb unions with R0Tb.
__global__ __launch_bounds__(256, 3)
void chunkC(const u16* __restrict__ qkv, float* __restrict__ ws,
            const u16* __restrict__ wbg, const u16* __restrict__ ktg,
            u16* __restrict__ ob) {
    __shared__ u16 Wb[4096], KTb[4096];
    __shared__ u16 RuT[64 * LSTR];           // R0Tb (first 4096) then RmTb
    __shared__ u16 Qhb[64 * LSTR], Kb[64 * LSTR], Vtb[64 * LSTR];
    u16* const R0Tb = RuT;
    u16* const RmTb = RuT;
    u16* const A1m = Kb;
    u16* const A2m = Vtb;

    const int cc = blockIdx.x;
    const int bh = cc >> 4, c = cc & 15;
    const int b = bh / NH, h = bh - b * NH;
    const int tid = threadIdx.x;
    const int w = tid >> 6, lane = tid & 63;
    const int ln = lane & 15, quad = lane >> 4;
    const int wr = w * 16;
    const u16* base = qkv + ((size_t)(b * T_ + c * CS)) * QKVW + h * HS;
    const u16* r0tg = (const u16*)(ws + OFF_R0);

    const int off = w * 1024;
    {
        const size_t bb = (size_t)cc * 4096;
#pragma unroll
        for (int i = 0; i < 2; ++i) {
            gll16(wbg  + bb + off + i * 512 + lane * 8, &Wb[off + i * 512]);
            gll16(ktg  + bb + off + i * 512 + lane * 8, &KTb[off + i * 512]);
            gll16(r0tg + bb + off + i * 512 + lane * 8, &R0Tb[off + i * 512]);
        }
    }
    {
        const int tr0 = w * 4 + quad;
        const int d0 = ln * 4;
        float qsc = __powf(LAM, (float)(tr0 + 1));
        float vsc = 1.0f / qsc;
        const float q16 = __powf(LAM, 16.0f);
        const float v16 = 1.0f / q16;
#pragma unroll
        for (int p = 0; p < 4; ++p) {
            const int t = p * 16 + tr0;
            const u16x4 qu = *(const u16x4*)(base + (size_t)t * QKVW + d0);
            const u16x4 ku = *(const u16x4*)(base + (size_t)t * QKVW + CDIM + d0);
            const u16x4 vu = *(const u16x4*)(base + (size_t)t * QKVW + 2 * CDIM + d0);
            u16x4 q4; q4.x = f2bf(bf2f(qu.x) * qsc); q4.y = f2bf(bf2f(qu.y) * qsc);
            q4.z = f2bf(bf2f(qu.z) * qsc); q4.w = f2bf(bf2f(qu.w) * qsc);
            u16x4 v4; v4.x = f2bf(bf2f(vu.x) * vsc); v4.y = f2bf(bf2f(vu.y) * vsc);
            v4.z = f2bf(bf2f(vu.z) * vsc); v4.w = f2bf(bf2f(vu.w) * vsc);
            *(u16x4*)&Qhb[t * LSTR + d0] = q4;
            *(u16x4*)&Kb[t * LSTR + d0] = ku;
            *(u16x4*)&Vtb[t * LSTR + d0] = v4;
            qsc *= q16; vsc *= v16;
        }
    }
    __syncthreads();

    // U loads issued early; latency hides under the a1/a2 strips
    const u16* Ugp = (const u16*)(ws + OFF_U) + (size_t)cc * 4096
                     + (size_t)(w * 64 + lane) * 16;
    const bf16x8 uu0 = *(const bf16x8*)&Ugp[0];
    const bf16x8 uu1 = *(const bf16x8*)&Ugp[8];

    f32x4 a1[4] = {}, a2[4] = {};
    mm_strip2<false,false>(Qhb, Kb,   wr, ln, quad, a1);
    mm_strip2<false,false>(Qhb, Vtb,  wr, ln, quad, a2);
    __syncthreads();

    const int row = wr + quad * 4;
#pragma unroll
    for (int nt = 0; nt < 4; ++nt) {
        const int col = nt * 16 + ln;
#pragma unroll
        for (int r = 0; r < 4; ++r) {
            const int t = row + r;
            A1m[t * LSTR + col] = (col <= t) ? f2bf(a1[nt][r]) : (u16)0;
            A2m[t * LSTR + col] = (col <= t) ? f2bf(a2[nt][r]) : (u16)0;
        }
    }

    f32x4 Oacc[4] = {}, wr0[4] = {};
    mm_strip2<false,true >(Qhb, R0Tb, wr, ln, quad, Oacc);
    mm_strip2<true ,true >(Wb,  R0Tb, wr, ln, quad, wr0);
#pragma unroll
    for (int nt = 0; nt < 4; ++nt) {
        const bf16x8 uu = (nt < 2) ? uu0 : uu1;
        const int o = (nt & 1) * 4;
        wr0[nt][0] += bf2f((u16)uu[o + 0]); wr0[nt][1] += bf2f((u16)uu[o + 1]);
        wr0[nt][2] += bf2f((u16)uu[o + 2]); wr0[nt][3] += bf2f((u16)uu[o + 3]);
    }
    __syncthreads();   // all R0Tb reads done; A1m/A2m writes visible

#pragma unroll
    for (int nt = 0; nt < 4; ++nt)
        *(u16x4*)&RmTb[(nt * 16 + ln) * LSTR + row] = f2bf4(wr0[nt]);
    __syncthreads();

    f32x4 O3[4] = {};
    mm_strip2<false,true >(A2m, KTb,  wr, ln, quad, Oacc);
    mm_strip2<false,false>(A1m, RmTb, wr, ln, quad, O3);

#pragma unroll
    for (int nt = 0; nt < 4; ++nt) {
        const int col = nt * 16 + ln;
#pragma unroll
        for (int r = 0; r < 4; ++r) {
            const float o = Oacc[nt][r] - BP * O3[nt][r];
            ob[((size_t)(b * T_ + c * CS + row + r)) * CDIM + h * HS + col] = f2bf(o);
        }
    }
}

// ------------------------------ launch ----------------------------------
extern "C" void kernel_launch(void* const* d_in, const int* in_sizes, int n_in,
                              void* d_out, int out_size, void* d_ws, size_t ws_size,
                              hipStream_t stream) {
    const float* x      = (const float*)d_in[0];   // (4,1024,768)
    const float* w_attn = (const float*)d_in[1];   // (768, 2304)
    const float* w_proj = (const float*)d_in[2];   // (768, 768)
    float* ws  = (float*)d_ws;
    u16* qkv = (u16*)ws;                  // bf16 normalized qkv
    u16* xb  = (u16*)(ws + OFF_XB);
    u16* waT = (u16*)(ws + OFF_WAT);
    u16* wpT = (u16*)(ws + OFF_WPT);      // free region, survives whole pipeline
    u16* ob  = (u16*)(ws + OFF_C);
    u16* wbg = (u16*)d_out;               // scratch: bf16 W  (swizzled)
    u16* ktg = (u16*)d_out + 768 * 4096;  // scratch: bf16 K^T (swizzled)

    // 0) all input casts in one launch
    cast_all_kernel<<<3648, 256, 0, stream>>>(x, w_attn, w_proj, xb, waT, wpT);

    // 1) qkv = norm(x @ w_attn). Grid 576 = 8 XCDs x (9x8 tile rect):
    //    per-XCD working set 3.3 MB < 4 MB L2 (default round-robin: ~10 MB).
    gemm_mfma<false, true, 4, 3, 2, 9, 8><<<576, 256, 0, stream>>>(
        xb, waT, nullptr, qkv, QKVW, CDIM);

    // 2) chunked WY scan (all MFMA); chunkB column-split 4x (bitwise identical)
    chunkA<<<768, 256, 0, stream>>>(qkv, ws, wbg, ktg);
    chunkB<<<192, 256, 0, stream>>>(ws, wbg, ktg);
    chunkC<<<768, 256, 0, stream>>>(qkv, ws, wbg, ktg, ob);

    // 3) y = o @ w_proj + x. Grid 384 = 8 XCDs x (6x8 tile rect), 2 MB/XCD.
    gemm_mfma<true, false, 2, 4, 1, 6, 8><<<384, 256, 0, stream>>>(
        ob, wpT, x, (float*)d_out, CDIM, CDIM);
}

// Round 7
// 156.219 us; speedup vs baseline: 1.0048x; 1.0048x over previous
//
#include <hip/hip_runtime.h>

typedef unsigned short u16;
typedef __attribute__((ext_vector_type(4))) unsigned short u16x4;
typedef __attribute__((ext_vector_type(8))) short bf16x8;
typedef __attribute__((ext_vector_type(4))) float f32x4;

#define B_ 4
#define T_ 1024
#define NH 12
#define HS 64
#define CDIM 768
#define QKVW 2304   // 3*CDIM
#define NC 16
#define CS 64
#define LAM 0.99f
#define BP  (0.01f/0.99f)
#define MROWS 4096
#define LSTR 72     // bf16 LDS row stride: 144B, 16B-aligned, 2-way banks (free)

// ws layout (float offsets). qkv bf16 at ws[0] (span 4718592 floats).
// [4718592, 9437184) is permanently free -> wpT lives there.
#define OFF_WPT 4718592
#define OFF_W  9437184
#define OFF_U  (OFF_W  + 768*4096)   // bf16 permuted U (u16, half-used)
#define OFF_C  (OFF_U  + 768*4096)   // bf16 permuted C; later bf16 ob (aliased)
#define OFF_R0 (OFF_C  + 768*4096)   // bf16 swizzled R0^T (u16)
#define OFF_XB (OFF_W)                       // bf16 x
#define OFF_WAT (OFF_W + 1572864)            // bf16 w_attn^T
// d_out doubles as scratch: wbg (bf16 W, swizzled) + ktg (bf16 K^T, swizzled)

__device__ __forceinline__ u16 f2bf(float f) {
    union { float f; unsigned u; } a; a.f = f;
    const unsigned r = a.u + 0x7FFF + ((a.u >> 16) & 1);
    return (u16)(r >> 16);
}
__device__ __forceinline__ float bf2f(u16 h) {
    union { unsigned u; float f; } a; a.u = ((unsigned)h) << 16; return a.f;
}
__device__ __forceinline__ u16x4 f2bf4(const f32x4 v) {
    u16x4 u; u.x = f2bf(v[0]); u.y = f2bf(v[1]); u.z = f2bf(v[2]); u.w = f2bf(v[3]);
    return u;
}
// swizzled stride-64 LDS index (matches the wbg/ktg global layout and the
// ks = kq ^ ((ln&7)*8) read path in mm_stripN's SWZ=true mode)
__device__ __forceinline__ int swz(int row, int col) {
    return row * 64 + (((col >> 3) ^ (row & 7)) << 3) + (col & 7);
}

// ---------------- merged cast kernel ------------------------------------
// blocks [0,3072): x -> bf16 xb (straight)
// blocks [3072,3504): w_attn [768][2304] -> waT [2304][768] bf16
// blocks [3504,3648): w_proj [768][768]  -> wpT [768][768]  bf16
__device__ __forceinline__ void tcast_body(const float* __restrict__ src,
                                           u16* __restrict__ dst,
                                           int Cn, int Rr, int bx, int by) {
    const int ln = threadIdx.x & 63, kg = threadIdx.x >> 6;
    const int n = bx * 64 + ln;
    const int kb = by * 64 + kg * 16;
    u16 tmp[16];
#pragma unroll
    for (int j = 0; j < 16; ++j)
        tmp[j] = f2bf(src[(size_t)(kb + j) * Cn + n]);
#pragma unroll
    for (int j4 = 0; j4 < 4; ++j4) {
        u16x4 u; u.x = tmp[j4*4]; u.y = tmp[j4*4+1]; u.z = tmp[j4*4+2]; u.w = tmp[j4*4+3];
        *(u16x4*)&dst[(size_t)n * Rr + kb + j4*4] = u;
    }
}

__global__ __launch_bounds__(256)
void cast_all_kernel(const float* __restrict__ x, const float* __restrict__ wa,
                     const float* __restrict__ wp, u16* __restrict__ xb,
                     u16* __restrict__ waT, u16* __restrict__ wpT) {
    const int bid = blockIdx.x;
    if (bid < 3072) {
        const size_t i = ((size_t)bid * 256 + threadIdx.x) * 4;
        const float4 v = *(const float4*)(x + i);
        u16x4 u;
        u.x = f2bf(v.x); u.y = f2bf(v.y); u.z = f2bf(v.z); u.w = f2bf(v.w);
        *(u16x4*)(xb + i) = u;
    } else if (bid < 3504) {
        const int idx = bid - 3072;
        tcast_body(wa, waT, QKVW, CDIM, idx % 36, idx / 36);
    } else {
        const int idx = bid - 3504;
        tcast_body(wp, wpT, CDIM, CDIM, idx % 12, idx / 12);
    }
}

// ---------------- MFMA GEMM: C[M,N] = A[M,K] @ Bt[N,K]^T ----------------
// Tile: (32*MI_T) x 128. 1D grid with XCD-aware RECT swizzle (neutral in
// R6 A/B but harmless; keeps per-XCD operand working set < 4 MB L2).
// Latency regime (K=768, 12 K-steps): small tiles + high blocks/CU is the
// proven lever (R4). Pure index remap -> bitwise identical output.
// NORM: per-64-col-group standardization epilogue, bf16 out. Else fp32 (+R).
__device__ __forceinline__ void gll16(const u16* g, u16* lds) {
    __builtin_amdgcn_global_load_lds(
        (const __attribute__((address_space(1))) unsigned*)g,
        (__attribute__((address_space(3))) unsigned*)lds, 16, 0, 0);
}

template<bool ADD_RES, bool NORM, int MI_T, int MINW, int XC, int RW, int RH>
__global__ __launch_bounds__(256, MINW)
void gemm_mfma(const u16* __restrict__ A, const u16* __restrict__ Bt,
               const float* __restrict__ R, void* __restrict__ Cout,
               int N, int K) {
    __shared__ u16 As[32 * MI_T * 64];
    __shared__ u16 Bs[128 * 64];
    const int tid  = threadIdx.x;
    const int wave = tid >> 6, lane = tid & 63;
    const int wm = wave >> 1, wn = wave & 1;
    const int ln = lane & 15, quad = lane >> 4;

    const int bid = blockIdx.x;
    const int xcd = bid & 7, slot = bid >> 3;
    const int tx = (xcd % XC) * RW + slot % RW;
    const int ty = (xcd / XC) * RH + slot / RW;
    const int m0 = ty * (32 * MI_T), n0 = tx * 128;

    const int rl = lane >> 3;
    const int kx = ((lane & 7) ^ rl) * 8;
    const u16* Ag = A + (size_t)(m0 + wave * (8 * MI_T) + rl) * K + kx;
    const u16* Bg = Bt + (size_t)(n0 + wave * 32 + rl) * K + kx;
    u16* AsW = &As[(wave * (8 * MI_T)) * 64];
    u16* BsW = &Bs[(wave * 32) * 64];

    f32x4 acc[MI_T][4] = {};

    for (int k0 = 0; k0 < K; k0 += 64) {
        __syncthreads();
#pragma unroll
        for (int c8 = 0; c8 < MI_T; ++c8)
            gll16(Ag + (size_t)(c8 * 8) * K + k0, AsW + c8 * 8 * 64);
#pragma unroll
        for (int c8 = 0; c8 < 4; ++c8)
            gll16(Bg + (size_t)(c8 * 8) * K + k0, BsW + c8 * 8 * 64);
        __syncthreads();
#pragma unroll
        for (int k32 = 0; k32 < 64; k32 += 32) {
            const int ko = (k32 + quad * 8) ^ ((ln & 7) * 8);
            bf16x8 af[MI_T], bfr[4];
#pragma unroll
            for (int mi = 0; mi < MI_T; ++mi)
                af[mi] = *(const bf16x8*)&As[(wm * (16 * MI_T) + mi * 16 + ln) * 64 + ko];
#pragma unroll
            for (int ni = 0; ni < 4; ++ni)
                bfr[ni] = *(const bf16x8*)&Bs[(wn * 64 + ni * 16 + ln) * 64 + ko];
#pragma unroll
            for (int mi = 0; mi < MI_T; ++mi)
#pragma unroll
                for (int ni = 0; ni < 4; ++ni)
                    acc[mi][ni] = __builtin_amdgcn_mfma_f32_16x16x32_bf16(
                        af[mi], bfr[ni], acc[mi][ni], 0, 0, 0);
        }
    }

#pragma unroll
    for (int mi = 0; mi < MI_T; ++mi) {
        const int rb = m0 + wm * (16 * MI_T) + mi * 16 + quad * 4;
#pragma unroll
        for (int r = 0; r < 4; ++r) {
            if (NORM) {
                const float a0 = acc[mi][0][r], a1 = acc[mi][1][r];
                const float a2 = acc[mi][2][r], a3 = acc[mi][3][r];
                float s1 = a0 + a1 + a2 + a3;
                float s2 = a0*a0 + a1*a1 + a2*a2 + a3*a3;
#pragma unroll
                for (int m = 1; m < 16; m <<= 1) {
                    s1 += __shfl_xor(s1, m, 64);
                    s2 += __shfl_xor(s2, m, 64);
                }
                const float mu = s1 * (1.0f / 64.0f);
                const float rs = rsqrtf((s2 - 64.0f * mu * mu) * (1.0f / 63.0f));
                u16* op = (u16*)Cout + (size_t)(rb + r) * N + n0 + wn * 64 + ln;
                op[0]  = f2bf((a0 - mu) * rs);
                op[16] = f2bf((a1 - mu) * rs);
                op[32] = f2bf((a2 - mu) * rs);
                op[48] = f2bf((a3 - mu) * rs);
            } else {
#pragma unroll
                for (int ni = 0; ni < 4; ++ni) {
                    const int col = n0 + wn * 64 + ni * 16 + ln;
                    float v = acc[mi][ni][r];
                    if (ADD_RES) v += R[(size_t)(rb + r) * N + col];
                    ((float*)Cout)[(size_t)(rb + r) * N + col] = v;
                }
            }
        }
    }
}

// ---------------- MFMA strip microkernels -------------------------------
template<bool ASWZ, bool BSWZ, int NT>
__device__ __forceinline__ void mm_stripN(const u16* A, const u16* Bq,
                                          int wr, int ln, int quad, f32x4 (&acc)[NT]) {
#pragma unroll
    for (int k0 = 0; k0 < 64; k0 += 32) {
        const int kq = k0 + quad * 8;
        const int ks = kq ^ ((ln & 7) * 8);
        const bf16x8 a = ASWZ ? *(const bf16x8*)&A[(wr + ln) * 64 + ks]
                              : *(const bf16x8*)&A[(wr + ln) * LSTR + kq];
#pragma unroll
        for (int nt = 0; nt < NT; ++nt) {
            const bf16x8 b = BSWZ ? *(const bf16x8*)&Bq[(nt * 16 + ln) * 64 + ks]
                                  : *(const bf16x8*)&Bq[(nt * 16 + ln) * LSTR + kq];
            acc[nt] = __builtin_amdgcn_mfma_f32_16x16x32_bf16(a, b, acc[nt], 0, 0, 0);
        }
    }
}

template<bool ASWZ, bool BSWZ>
__device__ __forceinline__ void mm_strip2(const u16* A, const u16* Bq,
                                          int wr, int ln, int quad, f32x4 (&acc)[4]) {
    mm_stripN<ASWZ, BSWZ, 4>(A, Bq, wr, ln, quad, acc);
}

// ---------------- Kernel A (MFMA): per-(bh,chunk) W, U, C ---------------
// All 5 LDS buffers in swizzled stride-64 layout: 5 x 8192 B = 40960 B
// -> 4 blocks/CU. All strip reads have row==ln (mod 8), so the SWZ=true
// read path applies throughout. Bitwise identical to LSTR version.
__global__ __launch_bounds__(256, 4)
void chunkA(const u16* __restrict__ qkv, float* __restrict__ ws,
            u16* __restrict__ wbg, u16* __restrict__ ktg) {
    __shared__ u16 Kb[4096], Vb[4096], KT[4096], VT[4096], NT[4096];
    u16* const Yb = Kb;
    u16* const Np = Vb;
    u16* const UT = NT;
    u16* const HbT = VT;   // VT dead after early c1 strip

    const int cc = blockIdx.x;
    const int bh = cc >> 4, c = cc & 15;
    const int b = bh / NH, h = bh - b * NH;
    const int tid = threadIdx.x;
    const int w = tid >> 6, lane = tid & 63;
    const int ln = lane & 15, quad = lane >> 4;
    const int wr = w * 16;
    const u16* base = qkv + ((size_t)(b * T_ + c * CS)) * QKVW + h * HS;

    {
        const int tr0 = w * 4 + quad;
        const int d0 = ln * 4;
        float vsc = __powf(LAM, -(float)(tr0 + 1));
        const float v16 = __powf(LAM, -16.0f);
#pragma unroll
        for (int p = 0; p < 4; ++p) {
            const int t = p * 16 + tr0;
            const u16x4 k4 = *(const u16x4*)(base + (size_t)t * QKVW + CDIM + d0);
            const u16x4 vu = *(const u16x4*)(base + (size_t)t * QKVW + 2 * CDIM + d0);
            u16x4 v4; v4.x = f2bf(bf2f(vu.x) * vsc); v4.y = f2bf(bf2f(vu.y) * vsc);
            v4.z = f2bf(bf2f(vu.z) * vsc); v4.w = f2bf(bf2f(vu.w) * vsc);
            *(u16x4*)&Kb[swz(t, d0)] = k4;
            *(u16x4*)&Vb[swz(t, d0)] = v4;
            KT[swz(d0 + 0, t)] = k4.x; KT[swz(d0 + 1, t)] = k4.y;
            KT[swz(d0 + 2, t)] = k4.z; KT[swz(d0 + 3, t)] = k4.w;
            VT[swz(d0 + 0, t)] = v4.x; VT[swz(d0 + 1, t)] = v4.y;
            VT[swz(d0 + 2, t)] = v4.z; VT[swz(d0 + 3, t)] = v4.w;
            vsc *= v16;
        }
    }
    __syncthreads();

    f32x4 accG[4] = {}, accH[4] = {}, c1[4] = {};
    mm_strip2<true,true>(Kb, Kb, wr, ln, quad, accG);   // G = K K^T
    mm_strip2<true,true>(Kb, Vb, wr, ln, quad, accH);   // H = K Vt^T
    mm_strip2<true,true>(VT, KT, wr, ln, quad, c1);     // c1 = Vt^T K (hoisted)
    __syncthreads();

#pragma unroll
    for (int nt = 0; nt < 4; ++nt) {
        const int col = nt * 16 + ln;
        u16x4 nvT, hvT;
#pragma unroll
        for (int r = 0; r < 4; ++r) {
            const int row = wr + quad * 4 + r;
            const float g = accG[nt][r];
            const u16 nv = (col < row) ? f2bf(BP * g) : (u16)0;
            Np[swz(row, col)] = nv;
            Yb[swz(row, col)] = (row == col) ? f2bf(1.0f)
                               : ((col < row) ? f2bf(-BP * g) : (u16)0);
            ((u16*)&nvT)[r] = nv;
            ((u16*)&hvT)[r] = (col < row) ? f2bf(accH[nt][r]) : (u16)0;
        }
        *(u16x4*)&NT[swz(col, wr + quad * 4)] = nvT;
        *(u16x4*)&HbT[swz(col, wr + quad * 4)] = hvT;
    }
    __syncthreads();

    for (int j = 0; j < 3; ++j) {
        f32x4 sq[4] = {};
        mm_strip2<true,true>(Np, NT, wr, ln, quad, sq);
        __syncthreads();
#pragma unroll
        for (int nt = 0; nt < 4; ++nt) {
            const int col = nt * 16 + ln;
            u16x4 sv;
#pragma unroll
            for (int r = 0; r < 4; ++r) {
                const u16 v = f2bf(sq[nt][r]);
                Np[swz(wr + quad * 4 + r, col)] = v;
                ((u16*)&sv)[r] = v;
            }
            *(u16x4*)&NT[swz(col, wr + quad * 4)] = sv;
        }
        __syncthreads();
        f32x4 ya[4];
#pragma unroll
        for (int nt = 0; nt < 4; ++nt)
#pragma unroll
            for (int r = 0; r < 4; ++r)
                ya[nt][r] = bf2f(Yb[swz(wr + quad * 4 + r, nt * 16 + ln)]);
        mm_strip2<true,true>(Yb, NT, wr, ln, quad, ya);
#pragma unroll
        for (int nt = 0; nt < 4; ++nt)
#pragma unroll
            for (int r = 0; r < 4; ++r)
                Yb[swz(wr + quad * 4 + r, nt * 16 + ln)] = f2bf(ya[nt][r]);
    }

    u16* Ugp = (u16*)(ws + OFF_U) + (size_t)cc * 4096;
    u16* Cgp = (u16*)(ws + OFF_C) + (size_t)cc * 4096;

    f32x4 wv[4] = {};
    mm_strip2<true,true>(Yb, KT, wr, ln, quad, wv);       // W = Y*K

    f32x4 m1[4] = {};
    mm_strip2<true,true>(Yb, HbT, wr, ln, quad, m1);      // M1 = Y*H_SL
#pragma unroll
    for (int nt = 0; nt < 4; ++nt)
#pragma unroll
        for (int r = 0; r < 4; ++r)
            Np[swz(wr + quad * 4 + r, nt * 16 + ln)] = f2bf(m1[nt][r]);

#pragma unroll
    for (int nt = 0; nt < 4; ++nt)
#pragma unroll
        for (int r = 0; r < 4; ++r)
            Yb[swz(wr + quad * 4 + r, nt * 16 + ln)] = f2bf(wv[nt][r]);

    f32x4 uv[4] = {};
    mm_strip2<true,true>(Np, KT, wr, ln, quad, uv);       // U = M1*K
#pragma unroll
    for (int nt = 0; nt < 4; ++nt)
        *(u16x4*)&Ugp[(size_t)(w * 64 + lane) * 16 + nt * 4] = f2bf4(uv[nt]);
    __syncthreads();
#pragma unroll
    for (int nt = 0; nt < 4; ++nt)
        *(u16x4*)&UT[swz(nt * 16 + ln, wr + quad * 4)] = f2bf4(uv[nt]);
    __syncthreads();

    f32x4 c2[4] = {};
    mm_strip2<true,true>(KT, UT, wr, ln, quad, c2);       // K^T U
#pragma unroll
    for (int nt = 0; nt < 4; ++nt) {
        const f32x4 cv = c1[nt] - BP * c2[nt];
        *(u16x4*)&Cgp[(size_t)(w * 64 + lane) * 16 + nt * 4] = f2bf4(cv);
    }

    // LDS layout == global swizzled layout: straight linear copy
    for (int e = tid; e < 512; e += 256) {
        *(bf16x8*)&wbg[(size_t)cc * 4096 + e * 8] = *(const bf16x8*)&Yb[e * 8];
        *(bf16x8*)&ktg[(size_t)cc * 4096 + e * 8] = *(const bf16x8*)&KT[e * 8];
    }
}

// ---------------- Kernel B (MFMA): sequential 16-chunk sweep ------------
// Column-split: 4 blocks per bh, each owning 16 state columns. Bitwise
// identical to the single-block version (column-separable recurrence).
__global__ __launch_bounds__(256)
void chunkB(float* __restrict__ ws, const u16* __restrict__ wbg,
            const u16* __restrict__ ktg) {
    __shared__ u16 WBs[2][4096], KTs[2][4096];
    __shared__ u16 RTb[16 * LSTR], PTb[16 * LSTR];

    const int bid = blockIdx.x;
    const int bh = bid >> 2, qtr = bid & 3;
    const int cb = qtr * 16;                 // global column base
    const int tid = threadIdx.x;
    const int w = tid >> 6, lane = tid & 63;
    const int ln = lane & 15, quad = lane >> 4;
    const int wr = w * 16;
    const float lam64 = __powf(LAM, 64.0f);
    u16* r0tg = (u16*)(ws + OFF_R0);

    f32x4 R[1] = {};

    for (int e = tid; e < 16 * LSTR; e += 256) RTb[e] = 0;

    const int off = w * 1024;
    {
        const size_t b0 = (size_t)(bh * 16) * 4096;
#pragma unroll
        for (int i = 0; i < 2; ++i) {
            gll16(wbg + b0 + off + i * 512 + lane * 8, &WBs[0][off + i * 512]);
            gll16(ktg + b0 + off + i * 512 + lane * 8, &KTs[0][off + i * 512]);
        }
    }
    __syncthreads();

    for (int c = 0; c < NC; ++c) {
        const int buf = c & 1;
        const size_t cc = (size_t)(bh * 16 + c);

        if (c + 1 < NC) {
            const size_t b1 = (cc + 1) * 4096;
#pragma unroll
            for (int i = 0; i < 2; ++i) {
                gll16(wbg + b1 + off + i * 512 + lane * 8, &WBs[buf ^ 1][off + i * 512]);
                gll16(ktg + b1 + off + i * 512 + lane * 8, &KTs[buf ^ 1][off + i * 512]);
            }
        }

        // C slice for this quarter's 16 cols, loaded early (hides latency)
        const u16* Cg = (const u16*)(ws + OFF_C) + cc * 4096
                        + (size_t)(w * 64 + lane) * 16 + qtr * 4;
        const u16x4 cu = *(const u16x4*)Cg;

        f32x4 p[1] = {};
        mm_stripN<true,false,1>(&WBs[buf][0], RTb, wr, ln, quad, p);  // P[:,cols]
        *(u16x4*)&PTb[ln * LSTR + wr + quad * 4] = f2bf4(p[0]);
        __syncthreads();

        f32x4 kp[1] = {};
        mm_stripN<true,false,1>(&KTs[buf][0], PTb, wr, ln, quad, kp); // K^T P

        u16* r0t = r0tg + cc * 4096;
        const int swzr = (wr + quad * 4) ^ ((ln & 7) * 8);
        const int x = cb + ln;                // global column index
        *(u16x4*)&r0t[x * 64 + swzr] = f2bf4(R[0]);
        f32x4 cv; cv[0] = bf2f(cu.x); cv[1] = bf2f(cu.y);
        cv[2] = bf2f(cu.z); cv[3] = bf2f(cu.w);
        R[0] = lam64 * (R[0] - BP * kp[0] + cv);
        *(u16x4*)&RTb[ln * LSTR + wr + quad * 4] = f2bf4(R[0]);
        __syncthreads();
    }
}

// ---------------- Kernel C (MFMA): outputs per (bh,chunk) ---------------
// LDS: 53248 B -> 3 blocks/CU. RmTb unions with R0Tb.
__global__ __launch_bounds__(256, 3)
void chunkC(const u16* __restrict__ qkv, float* __restrict__ ws,
            const u16* __restrict__ wbg, const u16* __restrict__ ktg,
            u16* __restrict__ ob) {
    __shared__ u16 Wb[4096], KTb[4096];
    __shared__ u16 RuT[64 * LSTR];           // R0Tb (first 4096) then RmTb
    __shared__ u16 Qhb[64 * LSTR], Kb[64 * LSTR], Vtb[64 * LSTR];
    u16* const R0Tb = RuT;
    u16* const RmTb = RuT;
    u16* const A1m = Kb;
    u16* const A2m = Vtb;

    const int cc = blockIdx.x;
    const int bh = cc >> 4, c = cc & 15;
    const int b = bh / NH, h = bh - b * NH;
    const int tid = threadIdx.x;
    const int w = tid >> 6, lane = tid & 63;
    const int ln = lane & 15, quad = lane >> 4;
    const int wr = w * 16;
    const u16* base = qkv + ((size_t)(b * T_ + c * CS)) * QKVW + h * HS;
    const u16* r0tg = (const u16*)(ws + OFF_R0);

    const int off = w * 1024;
    {
        const size_t bb = (size_t)cc * 4096;
#pragma unroll
        for (int i = 0; i < 2; ++i) {
            gll16(wbg  + bb + off + i * 512 + lane * 8, &Wb[off + i * 512]);
            gll16(ktg  + bb + off + i * 512 + lane * 8, &KTb[off + i * 512]);
            gll16(r0tg + bb + off + i * 512 + lane * 8, &R0Tb[off + i * 512]);
        }
    }
    {
        const int tr0 = w * 4 + quad;
        const int d0 = ln * 4;
        float qsc = __powf(LAM, (float)(tr0 + 1));
        float vsc = 1.0f / qsc;
        const float q16 = __powf(LAM, 16.0f);
        const float v16 = 1.0f / q16;
#pragma unroll
        for (int p = 0; p < 4; ++p) {
            const int t = p * 16 + tr0;
            const u16x4 qu = *(const u16x4*)(base + (size_t)t * QKVW + d0);
            const u16x4 ku = *(const u16x4*)(base + (size_t)t * QKVW + CDIM + d0);
            const u16x4 vu = *(const u16x4*)(base + (size_t)t * QKVW + 2 * CDIM + d0);
            u16x4 q4; q4.x = f2bf(bf2f(qu.x) * qsc); q4.y = f2bf(bf2f(qu.y) * qsc);
            q4.z = f2bf(bf2f(qu.z) * qsc); q4.w = f2bf(bf2f(qu.w) * qsc);
            u16x4 v4; v4.x = f2bf(bf2f(vu.x) * vsc); v4.y = f2bf(bf2f(vu.y) * vsc);
            v4.z = f2bf(bf2f(vu.z) * vsc); v4.w = f2bf(bf2f(vu.w) * vsc);
            *(u16x4*)&Qhb[t * LSTR + d0] = q4;
            *(u16x4*)&Kb[t * LSTR + d0] = ku;
            *(u16x4*)&Vtb[t * LSTR + d0] = v4;
            qsc *= q16; vsc *= v16;
        }
    }
    __syncthreads();

    // U loads issued early; latency hides under the a1/a2 strips
    const u16* Ugp = (const u16*)(ws + OFF_U) + (size_t)cc * 4096
                     + (size_t)(w * 64 + lane) * 16;
    const bf16x8 uu0 = *(const bf16x8*)&Ugp[0];
    const bf16x8 uu1 = *(const bf16x8*)&Ugp[8];

    f32x4 a1[4] = {}, a2[4] = {};
    mm_strip2<false,false>(Qhb, Kb,   wr, ln, quad, a1);
    mm_strip2<false,false>(Qhb, Vtb,  wr, ln, quad, a2);
    __syncthreads();

    const int row = wr + quad * 4;
#pragma unroll
    for (int nt = 0; nt < 4; ++nt) {
        const int col = nt * 16 + ln;
#pragma unroll
        for (int r = 0; r < 4; ++r) {
            const int t = row + r;
            A1m[t * LSTR + col] = (col <= t) ? f2bf(a1[nt][r]) : (u16)0;
            A2m[t * LSTR + col] = (col <= t) ? f2bf(a2[nt][r]) : (u16)0;
        }
    }

    f32x4 Oacc[4] = {}, wr0[4] = {};
    mm_strip2<false,true >(Qhb, R0Tb, wr, ln, quad, Oacc);
    mm_strip2<true ,true >(Wb,  R0Tb, wr, ln, quad, wr0);
#pragma unroll
    for (int nt = 0; nt < 4; ++nt) {
        const bf16x8 uu = (nt < 2) ? uu0 : uu1;
        const int o = (nt & 1) * 4;
        wr0[nt][0] += bf2f((u16)uu[o + 0]); wr0[nt][1] += bf2f((u16)uu[o + 1]);
        wr0[nt][2] += bf2f((u16)uu[o + 2]); wr0[nt][3] += bf2f((u16)uu[o + 3]);
    }
    __syncthreads();   // all R0Tb reads done; A1m/A2m writes visible

#pragma unroll
    for (int nt = 0; nt < 4; ++nt)
        *(u16x4*)&RmTb[(nt * 16 + ln) * LSTR + row] = f2bf4(wr0[nt]);
    __syncthreads();

    f32x4 O3[4] = {};
    mm_strip2<false,true >(A2m, KTb,  wr, ln, quad, Oacc);
    mm_strip2<false,false>(A1m, RmTb, wr, ln, quad, O3);

#pragma unroll
    for (int nt = 0; nt < 4; ++nt) {
        const int col = nt * 16 + ln;
#pragma unroll
        for (int r = 0; r < 4; ++r) {
            const float o = Oacc[nt][r] - BP * O3[nt][r];
            ob[((size_t)(b * T_ + c * CS + row + r)) * CDIM + h * HS + col] = f2bf(o);
        }
    }
}

// ------------------------------ launch ----------------------------------
extern "C" void kernel_launch(void* const* d_in, const int* in_sizes, int n_in,
                              void* d_out, int out_size, void* d_ws, size_t ws_size,
                              hipStream_t stream) {
    const float* x      = (const float*)d_in[0];   // (4,1024,768)
    const float* w_attn = (const float*)d_in[1];   // (768, 2304)
    const float* w_proj = (const float*)d_in[2];   // (768, 768)
    float* ws  = (float*)d_ws;
    u16* qkv = (u16*)ws;                  // bf16 normalized qkv
    u16* xb  = (u16*)(ws + OFF_XB);
    u16* waT = (u16*)(ws + OFF_WAT);
    u16* wpT = (u16*)(ws + OFF_WPT);      // free region, survives whole pipeline
    u16* ob  = (u16*)(ws + OFF_C);
    u16* wbg = (u16*)d_out;               // scratch: bf16 W  (swizzled)
    u16* ktg = (u16*)d_out + 768 * 4096;  // scratch: bf16 K^T (swizzled)

    // 0) all input casts in one launch
    cast_all_kernel<<<3648, 256, 0, stream>>>(x, w_attn, w_proj, xb, waT, wpT);

    // 1) qkv = norm(x @ w_attn). 64x128 tile -> 1152 blocks @ 4 blocks/CU
    //    (was 128x128, 576 blocks @ 3/CU): latency regime wants TLP.
    //    Grid 1152 = 8 XCDs x (9x16 tile rect), 3.3 MB/XCD working set.
    gemm_mfma<false, true, 2, 4, 2, 9, 16><<<1152, 256, 0, stream>>>(
        xb, waT, nullptr, qkv, QKVW, CDIM);

    // 2) chunked WY scan (all MFMA); chunkB column-split 4x (bitwise identical)
    chunkA<<<768, 256, 0, stream>>>(qkv, ws, wbg, ktg);
    chunkB<<<192, 256, 0, stream>>>(ws, wbg, ktg);
    chunkC<<<768, 256, 0, stream>>>(qkv, ws, wbg, ktg, ob);

    // 3) y = o @ w_proj + x. Grid 384 = 8 XCDs x (6x8 tile rect), 2 MB/XCD.
    gemm_mfma<true, false, 2, 4, 1, 6, 8><<<384, 256, 0, stream>>>(
        ob, wpT, x, (float*)d_out, CDIM, CDIM);
}